// Round 1
// baseline (1061.879 us; speedup 1.0000x reference)
//
#include <hip/hip_runtime.h>

typedef short short8 __attribute__((ext_vector_type(8)));
typedef float f32x4 __attribute__((ext_vector_type(4)));

#define MFMA16(a, b, c) __builtin_amdgcn_mfma_f32_16x16x32_bf16(a, b, c, 0, 0, 0)

static __device__ __forceinline__ unsigned short f2bf(float f) {
  union { float f; unsigned u; } v; v.f = f;
  return (unsigned short)((v.u + 0x7FFFu + ((v.u >> 16) & 1u)) >> 16);
}
static __device__ __forceinline__ unsigned pk2(float a, float b) {
  return (unsigned)f2bf(a) | ((unsigned)f2bf(b) << 16);
}
static __device__ __forceinline__ void async16(void* lds, const void* g) {
  __builtin_amdgcn_global_load_lds(
      (const __attribute__((address_space(1))) unsigned*)g,
      (__attribute__((address_space(3))) unsigned*)lds, 16, 0, 0);
}
static __device__ __forceinline__ float wsum64(float v) {
#pragma unroll
  for (int m = 1; m < 64; m <<= 1) v += __shfl_xor(v, m);
  return v;
}

// ---------------- K0: zero pooled + ponder accumulators ----------------
__global__ void k_zero(float* dout) {
  int i = blockIdx.x * 256 + threadIdx.x;
  if (i < 2048) dout[i] = 0.0f;
  if (i == 0) dout[2048 + 4194304] = 0.0f;
}

// ---------------- K1a: pack weights (bf16, transposed, pre-XOR-swizzled) ----
// w1p: [e][fq][kc][fl 128][kk 64], elem ^ ((fl&7)<<3)   (w1t[f][h] chunks)
// w2p: [e][fq][kc2][hd 256][kk 32], elem ^ ((hd&3)<<3)  (w2t[hd][f] chunks)
// wpt: [fq 2][kc 4][fl 128][kk 64], elem ^ ((fl&7)<<3)  (Wp^T[hd][k] chunks)
__global__ void k_pack(const float* __restrict__ w1, const float* __restrict__ w2,
                       const float* __restrict__ Wp, unsigned short* __restrict__ w1p,
                       unsigned short* __restrict__ w2p, unsigned short* __restrict__ wpt) {
  int i = blockIdx.x * 256 + threadIdx.x;  // one thread = 8 consecutive kk
  float v[8];
  if (i < 524288) {
    int kb = i & 7, fl = (i >> 3) & 127, kc = (i >> 10) & 3, fq = (i >> 12) & 3, e = i >> 14;
    int f = fq * 128 + fl;
#pragma unroll
    for (int j = 0; j < 8; ++j) v[j] = w1[(e * 256 + kc * 64 + kb * 8 + j) * 512 + f];
    int blk = i >> 10;  // e*16 + fq*4 + kc
    int dst = (fl * 64 + kb * 8) ^ ((fl & 7) << 3);
    uint4 pv;
    pv.x = pk2(v[0], v[1]); pv.y = pk2(v[2], v[3]);
    pv.z = pk2(v[4], v[5]); pv.w = pk2(v[6], v[7]);
    *(uint4*)(w1p + blk * 8192 + dst) = pv;
  } else if (i < 1048576) {
    int i2 = i - 524288;
    int kb = i2 & 3, hd = (i2 >> 2) & 255, kc2 = (i2 >> 10) & 3, fq = (i2 >> 12) & 3, e = i2 >> 14;
#pragma unroll
    for (int j = 0; j < 8; ++j) {
      int f = fq * 128 + kc2 * 32 + kb * 8 + j;
      v[j] = w2[(e * 512 + f) * 256 + hd];
    }
    int blk = i2 >> 10;  // e*16 + fq*4 + kc2
    int dst = (hd * 32 + kb * 8) ^ ((hd & 3) << 3);
    uint4 pv;
    pv.x = pk2(v[0], v[1]); pv.y = pk2(v[2], v[3]);
    pv.z = pk2(v[4], v[5]); pv.w = pk2(v[6], v[7]);
    *(uint4*)(w2p + blk * 8192 + dst) = pv;
  } else {
    int j3 = i - 1048576;
    if (j3 >= 8192) return;
    int kb = j3 & 7, fl = (j3 >> 3) & 127, kc = (j3 >> 10) & 3, fq = (j3 >> 12) & 1;
#pragma unroll
    for (int j = 0; j < 8; ++j) v[j] = Wp[(kc * 64 + kb * 8 + j) * 256 + fq * 128 + fl];
    int blk = j3 >> 10;
    int dst = (fl * 64 + kb * 8) ^ ((fl & 7) << 3);
    uint4 pv;
    pv.x = pk2(v[0], v[1]); pv.y = pk2(v[2], v[3]);
    pv.z = pk2(v[4], v[5]); pv.w = pk2(v[6], v[7]);
    *(uint4*)(wpt + blk * 8192 + dst) = pv;
  }
}

// ---------------- K1b: Wk = Wq @ keys^T, fp32, layout [k][e] ----------------
__global__ void k_wk(const float* __restrict__ Wq1, const float* __restrict__ Wq2,
                     const float* __restrict__ keys, float* __restrict__ Wk1,
                     float* __restrict__ Wk2) {
  const float* Wq = blockIdx.x ? Wq2 : Wq1;
  float* Wk = blockIdx.x ? Wk2 : Wk1;
  for (int o = threadIdx.x; o < 8192; o += 256) {
    int k = o >> 5, e = o & 31;
    float s = 0.f;
    for (int j = 0; j < 256; ++j) s += Wq[k * 256 + j] * keys[e * 256 + j];
    Wk[o] = s;
  }
}

// ---------------- K2: input projection (MFMA) ----------------
#define P_LDS_W 67584
#define P_LDS_BP 100352
#define P_LDS_TOT 101376

__launch_bounds__(512, 2)
__global__ void k_proj(const float* __restrict__ xin, const unsigned short* __restrict__ wpt,
                       const float* __restrict__ bp, float* __restrict__ tokf,
                       unsigned short* __restrict__ tokb) {
  extern __shared__ char smem[];
  const int tid = threadIdx.x;
  const int tb = blockIdx.x * 128;
  const int w = tid >> 6, l = tid & 63, l15 = l & 15, l4 = l >> 4;

  for (int s = tid; s < 4096; s += 512) {
    int row = s >> 5, c8 = s & 31;
    const float* src = xin + (tb + row) * 256 + c8 * 8;
    f32x4 v0 = *(const f32x4*)src;
    f32x4 v1 = *(const f32x4*)(src + 4);
    uint4 pv;
    pv.x = pk2(v0.x, v0.y); pv.y = pk2(v0.z, v0.w);
    pv.z = pk2(v1.x, v1.y); pv.w = pk2(v1.z, v1.w);
    *(uint4*)(smem + row * 528 + c8 * 16) = pv;
  }
  if (tid < 256) ((float*)(smem + P_LDS_BP))[tid] = bp[tid];
  __syncthreads();

  const int wv_f = w >> 2, wv_t = w & 3;
  for (int fq = 0; fq < 2; ++fq) {
    f32x4 acc[8];
#pragma unroll
    for (int i = 0; i < 8; ++i) acc[i] = (f32x4)(0.0f);
    const char* cbase = (const char*)(wpt + (fq * 4) * 8192);
    {
      char* dst = smem + P_LDS_W;
      async16(dst + w * 2048, cbase + w * 2048 + l * 16);
      async16(dst + w * 2048 + 1024, cbase + w * 2048 + 1024 + l * 16);
    }
    __syncthreads();
    for (int kc = 0; kc < 4; ++kc) {
      int cur = kc & 1;
      if (kc < 3) {
        char* dst = smem + P_LDS_W + (cur ^ 1) * 16384;
        const char* src = cbase + (kc + 1) * 16384;
        async16(dst + w * 2048, src + w * 2048 + l * 16);
        async16(dst + w * 2048 + 1024, src + w * 2048 + 1024 + l * 16);
      }
      const char* Wc = smem + P_LDS_W + cur * 16384;
#pragma unroll
      for (int ks = 0; ks < 2; ++ks) {
        short8 af[4], bfr[2];
#pragma unroll
        for (int fr = 0; fr < 4; ++fr) {
          int frow = wv_f * 64 + fr * 16 + l15;
          int off = (frow * 128 + ks * 64 + l4 * 16) ^ ((frow & 7) << 4);
          af[fr] = *(const short8*)(Wc + off);
        }
#pragma unroll
        for (int tf = 0; tf < 2; ++tf) {
          int tok = wv_t * 32 + tf * 16 + l15;
          bfr[tf] = *(const short8*)(smem + tok * 528 + kc * 128 + ks * 64 + l4 * 16);
        }
#pragma unroll
        for (int fr = 0; fr < 4; ++fr)
#pragma unroll
          for (int tf = 0; tf < 2; ++tf)
            acc[fr * 2 + tf] = MFMA16(af[fr], bfr[tf], acc[fr * 2 + tf]);
      }
      __syncthreads();
    }
    const float* BP = (const float*)(smem + P_LDS_BP);
#pragma unroll
    for (int fr = 0; fr < 4; ++fr) {
      int hd0 = fq * 128 + wv_f * 64 + fr * 16 + l4 * 4;
      f32x4 bv = *(const f32x4*)(BP + hd0);
#pragma unroll
      for (int tf = 0; tf < 2; ++tf) {
        int tok = tb + wv_t * 32 + tf * 16 + l15;
        f32x4 o = acc[fr * 2 + tf] + bv;
        *(f32x4*)(tokf + tok * 256 + hd0) = o;
        uint2 hv; hv.x = pk2(o.x, o.y); hv.y = pk2(o.z, o.w);
        *(uint2*)(tokb + tok * 256 + hd0) = hv;
      }
    }
  }
}

// ---------------- K3: router 1 (fp32) ----------------
__global__ void k_router1(const float* __restrict__ tokf, const float* __restrict__ wk1,
                          float* __restrict__ probs1, int* __restrict__ top1) {
  __shared__ float WK[8192];
  const int tid = threadIdx.x;
  for (int i = tid; i < 8192; i += 256) WK[i] = wk1[i];
  __syncthreads();
  const int w = tid >> 6, l = tid & 63;
  const int e = l & 31, half = l >> 5;
  for (int tt = 0; tt < 16; ++tt) {
    int t = blockIdx.x * 64 + w * 16 + tt;
    const float* row = tokf + t * 256 + half * 128;
    const float* wkh = WK + half * 128 * 32 + e;
    float s = 0.f;
    for (int kk = 0; kk < 128; ++kk) s += row[kk] * wkh[kk * 32];
    s += __shfl_xor(s, 32);
    s *= 0.0625f;  // 1/sqrt(256), TEMP=1
    float m = s;
#pragma unroll
    for (int off = 16; off > 0; off >>= 1) m = fmaxf(m, __shfl_xor(m, off, 32));
    float ex = __expf(s - m);
    float sum = ex;
#pragma unroll
    for (int off = 16; off > 0; off >>= 1) sum += __shfl_xor(sum, off, 32);
    if (l < 32) probs1[t * 32 + e] = ex / sum;
    float bs = s; int bi = e;
#pragma unroll
    for (int off = 16; off > 0; off >>= 1) {
      float os = __shfl_xor(bs, off, 32);
      int oi = __shfl_xor(bi, off, 32);
      if (os > bs || (os == bs && oi < bi)) { bs = os; bi = oi; }
    }
    if (l == 0) top1[t] = bi;
  }
}

// ---------------- K4: fused expert bank (both hops) ----------------
#define B_LDS_H 67584
#define B_LDS_W 102400
#define B_LDS_PR 135168
#define B_LDS_B1 143360
#define B_LDS_TOT 145408

__launch_bounds__(512, 2)
__global__ void k_bank(const unsigned short* __restrict__ xg, const float* __restrict__ probsg,
                       const float* __restrict__ b1g, const unsigned short* __restrict__ w1p,
                       const unsigned short* __restrict__ w2p, float* __restrict__ partg) {
  extern __shared__ char smem[];
  const int tid = threadIdx.x;
  const int tile = blockIdx.x & 127, grp = blockIdx.x >> 7;
  const int tb = tile * 128;
  const int w = tid >> 6, l = tid & 63, l15 = l & 15, l4 = l >> 4;

  {
    const unsigned short* xrow = xg + tb * 256;
    for (int s = tid; s < 4096; s += 512) {
      int row = s >> 5, c8 = s & 31;
      uint4 v = *(const uint4*)(xrow + row * 256 + c8 * 8);
      *(uint4*)(smem + row * 528 + c8 * 16) = v;
    }
    float* PRL = (float*)(smem + B_LDS_PR);
    for (int s = tid; s < 2048; s += 512) {
      int e = s >> 7, t = s & 127;
      PRL[s] = probsg[(tb + t) * 32 + grp * 16 + e];
    }
  }

  f32x4 acc2[16];
#pragma unroll
  for (int i = 0; i < 16; ++i) acc2[i] = (f32x4)(0.0f);

  const int wv_f = w >> 2, wv_t = w & 3;   // GEMM1' wave grid
  const int wv_h = w >> 1, wv_t2 = w & 1;  // GEMM2' wave grid

  __syncthreads();

  for (int e = 0; e < 16; ++e) {
    const int eg = grp * 16 + e;
    ((float*)(smem + B_LDS_B1))[tid] = b1g[eg * 512 + tid];
    for (int fq = 0; fq < 4; ++fq) {
      // ---- GEMM1': D[f 128][tok 128] = w1t . x^T, K=256 (4 chunks of 64)
      f32x4 acc1[8];
#pragma unroll
      for (int i = 0; i < 8; ++i) acc1[i] = (f32x4)(0.0f);
      const char* cbase = (const char*)(w1p + ((eg * 4 + fq) * 4) * 8192);
      {
        char* dst = smem + B_LDS_W;
        async16(dst + w * 2048, cbase + w * 2048 + l * 16);
        async16(dst + w * 2048 + 1024, cbase + w * 2048 + 1024 + l * 16);
      }
      __syncthreads();
      for (int kc = 0; kc < 4; ++kc) {
        int cur = kc & 1;
        if (kc < 3) {
          char* dst = smem + B_LDS_W + (cur ^ 1) * 16384;
          const char* src = cbase + (kc + 1) * 16384;
          async16(dst + w * 2048, src + w * 2048 + l * 16);
          async16(dst + w * 2048 + 1024, src + w * 2048 + 1024 + l * 16);
        }
        const char* Wc = smem + B_LDS_W + cur * 16384;
#pragma unroll
        for (int ks = 0; ks < 2; ++ks) {
          short8 af[4], bfr[2];
#pragma unroll
          for (int fr = 0; fr < 4; ++fr) {
            int frow = wv_f * 64 + fr * 16 + l15;
            int off = (frow * 128 + ks * 64 + l4 * 16) ^ ((frow & 7) << 4);
            af[fr] = *(const short8*)(Wc + off);
          }
#pragma unroll
          for (int tf = 0; tf < 2; ++tf) {
            int tok = wv_t * 32 + tf * 16 + l15;
            bfr[tf] = *(const short8*)(smem + tok * 528 + kc * 128 + ks * 64 + l4 * 16);
          }
#pragma unroll
          for (int fr = 0; fr < 4; ++fr)
#pragma unroll
            for (int tf = 0; tf < 2; ++tf)
              acc1[fr * 2 + tf] = MFMA16(af[fr], bfr[tf], acc1[fr * 2 + tf]);
        }
        __syncthreads();
      }
      // ---- epilogue: h = relu(d + b1) * p -> H lds [tok][f-quarter] (padded)
      {
        const float* B1L = (const float*)(smem + B_LDS_B1) + fq * 128;
        const float* PRL = (const float*)(smem + B_LDS_PR) + e * 128;
#pragma unroll
        for (int fr = 0; fr < 4; ++fr) {
          int f0 = wv_f * 64 + fr * 16 + l4 * 4;
          f32x4 bv = *(const f32x4*)(B1L + f0);
#pragma unroll
          for (int tf = 0; tf < 2; ++tf) {
            int tok = wv_t * 32 + tf * 16 + l15;
            float p = PRL[tok];
            f32x4 a = acc1[fr * 2 + tf];
            float h0 = fmaxf(a.x + bv.x, 0.f) * p;
            float h1 = fmaxf(a.y + bv.y, 0.f) * p;
            float h2 = fmaxf(a.z + bv.z, 0.f) * p;
            float h3 = fmaxf(a.w + bv.w, 0.f) * p;
            uint2 hv; hv.x = pk2(h0, h1); hv.y = pk2(h2, h3);
            *(uint2*)(smem + B_LDS_H + tok * 272 + f0 * 2) = hv;
          }
        }
      }
      // ---- GEMM2': acc2[hd 256][tok 128] += w2t . h^T, K=128 (4 chunks of 32)
      const char* cbase2 = (const char*)(w2p + ((eg * 4 + fq) * 4) * 8192);
      {
        char* dst = smem + B_LDS_W;
        async16(dst + w * 2048, cbase2 + w * 2048 + l * 16);
        async16(dst + w * 2048 + 1024, cbase2 + w * 2048 + 1024 + l * 16);
      }
      __syncthreads();
      for (int kc = 0; kc < 4; ++kc) {
        int cur = kc & 1;
        if (kc < 3) {
          char* dst = smem + B_LDS_W + (cur ^ 1) * 16384;
          const char* src = cbase2 + (kc + 1) * 16384;
          async16(dst + w * 2048, src + w * 2048 + l * 16);
          async16(dst + w * 2048 + 1024, src + w * 2048 + 1024 + l * 16);
        }
        const char* Wc = smem + B_LDS_W + cur * 16384;
        short8 a2[4], b2f[4];
#pragma unroll
        for (int hr = 0; hr < 4; ++hr) {
          int hd = wv_h * 64 + hr * 16 + l15;
          int off = (hd * 64 + l4 * 16) ^ ((hd & 3) << 4);
          a2[hr] = *(const short8*)(Wc + off);
        }
#pragma unroll
        for (int tf = 0; tf < 4; ++tf) {
          int tok = wv_t2 * 64 + tf * 16 + l15;
          b2f[tf] = *(const short8*)(smem + B_LDS_H + tok * 272 + kc * 64 + l4 * 16);
        }
#pragma unroll
        for (int hr = 0; hr < 4; ++hr)
#pragma unroll
          for (int tf = 0; tf < 4; ++tf)
            acc2[hr * 4 + tf] = MFMA16(a2[hr], b2f[tf], acc2[hr * 4 + tf]);
        __syncthreads();
      }
    }  // fq
  }    // e

  float* pout = partg + grp * (16384 * 256);
#pragma unroll
  for (int hr = 0; hr < 4; ++hr) {
    int hd0 = wv_h * 64 + hr * 16 + l4 * 4;
#pragma unroll
    for (int tf = 0; tf < 4; ++tf) {
      int tok = tb + wv_t2 * 64 + tf * 16 + l15;
      *(f32x4*)(pout + tok * 256 + hd0) = acc2[hr * 4 + tf];
    }
  }
}

// ---------------- K5: hop1 reduce + halt + router2 ----------------
#define M_PRB 65536
#define M_AUX 73728
#define M_TBL 106496
#define M_PSUM 110592
#define M_TOT 110656

__launch_bounds__(512)
__global__ void k_mid(const float* __restrict__ partg, const float* __restrict__ probs1,
                      const float* __restrict__ b2g, const float* __restrict__ hlg,
                      const float* __restrict__ hlb, const float* __restrict__ hwg,
                      const float* __restrict__ hbg, const float* __restrict__ wk2,
                      const float* __restrict__ tbias, const int* __restrict__ top1,
                      float* __restrict__ hop1f, unsigned short* __restrict__ hop1b,
                      float* __restrict__ haltg, float* __restrict__ probs2,
                      float* __restrict__ dout) {
  extern __shared__ char smem[];
  const int tid = threadIdx.x;
  const int tb = blockIdx.x * 64;
  float* ROWS = (float*)smem;
  float* PRB = (float*)(smem + M_PRB);
  float* AUX = (float*)(smem + M_AUX);

  for (int i = tid; i < 2048; i += 512) PRB[i] = probs1[tb * 32 + i];
  for (int i = tid; i < 8192; i += 512) AUX[i] = b2g[i];
  __syncthreads();

  const float* p0 = partg;
  const float* p1 = partg + 16384 * 256;
  for (int i = tid; i < 4096; i += 512) {
    int t = i >> 6, h4 = i & 63;
    int gi = (tb + t) * 256 + h4 * 4;
    f32x4 v = *(const f32x4*)(p0 + gi) + *(const f32x4*)(p1 + gi);
    const float* pr = PRB + t * 32;
    for (int e = 0; e < 32; ++e) v += pr[e] * *(const f32x4*)(AUX + e * 256 + h4 * 4);
    *(f32x4*)(ROWS + t * 256 + h4 * 4) = v;
    *(f32x4*)(hop1f + gi) = v;
    uint2 hv; hv.x = pk2(v.x, v.y); hv.y = pk2(v.z, v.w);
    *(uint2*)(hop1b + gi) = hv;
  }
  __syncthreads();
  for (int i = tid; i < 8192; i += 512) AUX[i] = wk2[i];
  float* TBL = (float*)(smem + M_TBL);
  for (int i = tid; i < 1024; i += 512) TBL[i] = tbias[i];
  __syncthreads();

  const int w = tid >> 6, l = tid & 63;
  const int e = l & 31, half = l >> 5;
  float pond = 0.f;
  for (int tt = 0; tt < 8; ++tt) {
    int t = w * 8 + tt, tg = tb + t;
    const float* row = ROWS + t * 256;
    f32x4 x4 = *(const f32x4*)(row + l * 4);
    float mu = wsum64(x4.x + x4.y + x4.z + x4.w) * (1.f / 256.f);
    f32x4 d = x4 - mu;
    float var = wsum64(d.x * d.x + d.y * d.y + d.z * d.z + d.w * d.w) * (1.f / 256.f);
    float rstd = rsqrtf(var + 1e-5f);
    f32x4 g4 = *(const f32x4*)(hlg + l * 4);
    f32x4 b4 = *(const f32x4*)(hlb + l * 4);
    f32x4 w4 = *(const f32x4*)(hwg + l * 4);
    f32x4 y = d * rstd * g4 + b4;
    float z = wsum64(y.x * w4.x + y.y * w4.y + y.z * w4.z + y.w * w4.w);
    float hp = 1.f / (1.f + __expf(-(z + hbg[0])));
    if (l == 0) { haltg[tg] = hp; pond += 1.f - hp; }
    // router 2
    const float* rh = row + half * 128;
    const float* wkh = AUX + half * 128 * 32 + e;
    float sc = 0.f;
    for (int kk = 0; kk < 128; ++kk) sc += rh[kk] * wkh[kk * 32];
    sc += __shfl_xor(sc, 32);
    sc = sc * 0.0625f + TBL[top1[tg] * 32 + e];
    float m = sc;
#pragma unroll
    for (int off = 16; off > 0; off >>= 1) m = fmaxf(m, __shfl_xor(m, off, 32));
    float ex = __expf(sc - m);
    float sum = ex;
#pragma unroll
    for (int off = 16; off > 0; off >>= 1) sum += __shfl_xor(sum, off, 32);
    if (l < 32) probs2[tg * 32 + e] = ex / sum;
  }
  float* PS = (float*)(smem + M_PSUM);
  if (l == 0) PS[w] = pond;
  __syncthreads();
  if (tid == 0) {
    float tot = 0.f;
    for (int i = 0; i < 8; ++i) tot += PS[i];
    atomicAdd(dout + 2048 + 4194304, tot * (0.01f / 16384.f));
  }
}

// ---------------- K7: final mix + LN + pooled ----------------
#define F_PRB 65536
#define F_B2 73728
#define F_PSUM 106496
#define F_TOT 114688

__launch_bounds__(512)
__global__ void k_final(const float* __restrict__ partg, const float* __restrict__ probs2,
                        const float* __restrict__ b2g, const float* __restrict__ tokf,
                        const float* __restrict__ hop1f, const float* __restrict__ haltg,
                        const float* __restrict__ ng, const float* __restrict__ nbv,
                        float* __restrict__ dout) {
  extern __shared__ char smem[];
  const int tid = threadIdx.x;
  const int tb = blockIdx.x * 64;
  const int batch = blockIdx.x >> 5;
  float* ROWS = (float*)smem;
  float* PRB = (float*)(smem + F_PRB);
  float* B2L = (float*)(smem + F_B2);

  for (int i = tid; i < 2048; i += 512) PRB[i] = probs2[tb * 32 + i];
  for (int i = tid; i < 8192; i += 512) B2L[i] = b2g[i];
  __syncthreads();

  const float* p0 = partg;
  const float* p1 = partg + 16384 * 256;
  for (int i = tid; i < 4096; i += 512) {
    int t = i >> 6, h4 = i & 63;
    int gi = (tb + t) * 256 + h4 * 4;
    f32x4 h2 = *(const f32x4*)(p0 + gi) + *(const f32x4*)(p1 + gi);
    const float* pr = PRB + t * 32;
    for (int e = 0; e < 32; ++e) h2 += pr[e] * *(const f32x4*)(B2L + e * 256 + h4 * 4);
    float hp = haltg[tb + t];
    f32x4 h1 = *(const f32x4*)(hop1f + gi);
    f32x4 tk = *(const f32x4*)(tokf + gi);
    f32x4 pre = tk + hp * h1 + (1.f - hp) * h2;
    *(f32x4*)(ROWS + t * 256 + h4 * 4) = pre;
  }
  __syncthreads();
  const int w = tid >> 6, l = tid & 63;
  f32x4 pacc = (f32x4)(0.0f);
  f32x4 g4 = *(const f32x4*)(ng + l * 4);
  f32x4 b4 = *(const f32x4*)(nbv + l * 4);
  for (int tt = 0; tt < 8; ++tt) {
    int t = w * 8 + tt, tg = tb + t;
    f32x4 x4 = *(const f32x4*)(ROWS + t * 256 + l * 4);
    float mu = wsum64(x4.x + x4.y + x4.z + x4.w) * (1.f / 256.f);
    f32x4 d = x4 - mu;
    float var = wsum64(d.x * d.x + d.y * d.y + d.z * d.z + d.w * d.w) * (1.f / 256.f);
    float rstd = rsqrtf(var + 1e-5f);
    f32x4 y = d * rstd * g4 + b4;
    *(f32x4*)(dout + 2048 + tg * 256 + l * 4) = y;
    pacc += y;
  }
  float* PS = (float*)(smem + F_PSUM);
  *(f32x4*)(PS + w * 256 + l * 4) = pacc;
  __syncthreads();
  if (tid < 256) {
    float s = 0.f;
    for (int ww = 0; ww < 8; ++ww) s += PS[ww * 256 + tid];
    atomicAdd(dout + batch * 256 + tid, s * (1.f / 2048.f));
  }
}

extern "C" void kernel_launch(void* const* d_in, const int* in_sizes, int n_in,
                              void* d_out, int out_size, void* d_ws, size_t ws_size,
                              hipStream_t stream) {
  (void)in_sizes; (void)n_in; (void)out_size; (void)ws_size;
  const float* tokens_in = (const float*)d_in[0];
  const float* Wp = (const float*)d_in[1];
  const float* bp = (const float*)d_in[2];
  const float* Wq1 = (const float*)d_in[3];
  const float* Wq2 = (const float*)d_in[4];
  const float* keys = (const float*)d_in[5];
  const float* tbias = (const float*)d_in[6];
  const float* hlg = (const float*)d_in[7];
  const float* hlb = (const float*)d_in[8];
  const float* hw = (const float*)d_in[9];
  const float* hb = (const float*)d_in[10];
  const float* w1 = (const float*)d_in[11];
  const float* b1 = (const float*)d_in[12];
  const float* w2 = (const float*)d_in[13];
  const float* b2 = (const float*)d_in[14];
  const float* ng = (const float*)d_in[15];
  const float* nb = (const float*)d_in[16];
  float* out = (float*)d_out;
  char* ws = (char*)d_ws;

  unsigned short* w1p = (unsigned short*)(ws + 0);
  unsigned short* w2p = (unsigned short*)(ws + 8388608);
  unsigned short* wpt = (unsigned short*)(ws + 16777216);
  float* tokf = (float*)(ws + 16908288);
  unsigned short* tokb = (unsigned short*)(ws + 33685504);
  float* probs1 = (float*)(ws + 42074112);
  int* top1 = (int*)(ws + 44171264);
  float* hop1f = (float*)(ws + 44236800);
  unsigned short* hop1b = (unsigned short*)(ws + 61014016);
  float* haltg = (float*)(ws + 69402624);
  float* probs2 = (float*)(ws + 69468160);
  float* wk1 = (float*)(ws + 71565312);
  float* wk2 = (float*)(ws + 71598080);
  float* part = (float*)(ws + 71630848);  // 2 x 16384 x 256 f32

  k_zero<<<dim3(8), dim3(256), 0, stream>>>(out);
  k_pack<<<dim3(4128), dim3(256), 0, stream>>>(w1, w2, Wp, w1p, w2p, wpt);
  k_wk<<<dim3(2), dim3(256), 0, stream>>>(Wq1, Wq2, keys, wk1, wk2);
  k_proj<<<dim3(128), dim3(512), P_LDS_TOT, stream>>>(tokens_in, wpt, bp, tokf, tokb);
  k_router1<<<dim3(256), dim3(256), 0, stream>>>(tokf, wk1, probs1, top1);
  k_bank<<<dim3(256), dim3(512), B_LDS_TOT, stream>>>(tokb, probs1, b1, w1p, w2p, part);
  k_mid<<<dim3(256), dim3(512), M_TOT, stream>>>(part, probs1, b2, hlg, hlb, hw, hb, wk2,
                                                 tbias, top1, hop1f, hop1b, haltg, probs2, out);
  k_bank<<<dim3(256), dim3(512), B_LDS_TOT, stream>>>(hop1b, probs2, b1, w1p, w2p, part);
  k_final<<<dim3(256), dim3(512), F_TOT, stream>>>(part, probs2, b2, tokf, hop1f, haltg, ng, nb, out);
}